// Round 3
// baseline (82.081 us; speedup 1.0000x reference)
//
#include <hip/hip_runtime.h>

// DeepPoly ReLU bound propagation — pure elementwise, HBM-bound streaming.
// 3 f32 in, 3 f32 out, N = 16.7M (800 MB traffic, no reuse).
// Round 3: same as round 2 but with clang ext_vector float4 (the nontemporal
// builtins reject HIP_vector_type structs).

#define UNROLL 4

typedef float f32x4 __attribute__((ext_vector_type(4)));

__device__ __forceinline__ void deeppoly_relu_one(float xf, float lf, float uf,
                                                  float& xo, float& lo_o, float& up_o) {
    xo = fmaxf(xf, 0.0f);
    const bool neg = (uf <= 0.0f);          // fully inactive
    const bool pos = (lf >= 0.0f);          // fully active (after neg)
    const bool crossing = (!neg) && (!pos);
    const float denom = crossing ? (uf - lf) : 1.0f;  // >0 when crossing
    const float su = (uf / denom) * uf;     // slope * u (uniform divide, no divergence)
    lo_o = neg ? 0.0f : (pos ? uf : lf);
    up_o = neg ? 0.0f : (pos ? uf : su);
}

__device__ __forceinline__ void relu_vec4(f32x4 xv, f32x4 lv, f32x4 uv,
                                          f32x4& xo, f32x4& lo_o, f32x4& up_o) {
    #pragma unroll
    for (int j = 0; j < 4; ++j) {
        float a, b, c;
        deeppoly_relu_one(xv[j], lv[j], uv[j], a, b, c);
        xo[j] = a; lo_o[j] = b; up_o[j] = c;
    }
}

__global__ void __launch_bounds__(256) deeppoly_relu_kernel(
    const f32x4* __restrict__ x,
    const f32x4* __restrict__ lo,
    const f32x4* __restrict__ up,
    f32x4* __restrict__ x_out,
    f32x4* __restrict__ lo_out,
    f32x4* __restrict__ up_out,
    int n4)
{
    const int stride = gridDim.x * blockDim.x;
    int base = blockIdx.x * blockDim.x + threadIdx.x;

    // Full-unroll fast path: all UNROLL indices in range.
    for (; base + (UNROLL - 1) * stride < n4; base += UNROLL * stride) {
        f32x4 xv[UNROLL], lv[UNROLL], uv[UNROLL];
        #pragma unroll
        for (int k = 0; k < UNROLL; ++k) {
            const int i = base + k * stride;
            xv[k] = __builtin_nontemporal_load(&x[i]);
            lv[k] = __builtin_nontemporal_load(&lo[i]);
            uv[k] = __builtin_nontemporal_load(&up[i]);
        }
        #pragma unroll
        for (int k = 0; k < UNROLL; ++k) {
            f32x4 xo, lv_o, uv_o;
            relu_vec4(xv[k], lv[k], uv[k], xo, lv_o, uv_o);
            const int i = base + k * stride;
            __builtin_nontemporal_store(xo,   &x_out[i]);
            __builtin_nontemporal_store(lv_o, &lo_out[i]);
            __builtin_nontemporal_store(uv_o, &up_out[i]);
        }
    }
    // Remainder (partial unroll window).
    for (; base < n4; base += stride) {
        f32x4 xv = __builtin_nontemporal_load(&x[base]);
        f32x4 lv = __builtin_nontemporal_load(&lo[base]);
        f32x4 uv = __builtin_nontemporal_load(&up[base]);
        f32x4 xo, lv_o, uv_o;
        relu_vec4(xv, lv, uv, xo, lv_o, uv_o);
        __builtin_nontemporal_store(xo,   &x_out[base]);
        __builtin_nontemporal_store(lv_o, &lo_out[base]);
        __builtin_nontemporal_store(uv_o, &up_out[base]);
    }
}

// Scalar tail for N not divisible by 4 (not expected at N=16.7M).
__global__ void deeppoly_relu_tail(
    const float* __restrict__ x,
    const float* __restrict__ lo,
    const float* __restrict__ up,
    float* __restrict__ x_out,
    float* __restrict__ lo_out,
    float* __restrict__ up_out,
    int start, int n)
{
    int i = start + blockIdx.x * blockDim.x + threadIdx.x;
    if (i < n) {
        float xo, lo_o, up_o;
        deeppoly_relu_one(x[i], lo[i], up[i], xo, lo_o, up_o);
        x_out[i] = xo; lo_out[i] = lo_o; up_out[i] = up_o;
    }
}

extern "C" void kernel_launch(void* const* d_in, const int* in_sizes, int n_in,
                              void* d_out, int out_size, void* d_ws, size_t ws_size,
                              hipStream_t stream) {
    const float* x  = (const float*)d_in[0];
    const float* lo = (const float*)d_in[1];
    const float* up = (const float*)d_in[2];
    float* out = (float*)d_out;

    const int n = in_sizes[0];
    float* x_out  = out;
    float* lo_out = out + (size_t)n;
    float* up_out = out + 2 * (size_t)n;

    const int n4 = n / 4;
    const int block = 256;
    // One full-unroll pass: grid*block*UNROLL ≈ n4 (16.7M/4/4/256 = 4096 blocks
    // = 16 blocks/CU), capped for safety on other sizes.
    int grid = (n4 + block * UNROLL - 1) / (block * UNROLL);
    if (grid > 8192) grid = 8192;
    if (grid > 0) {
        deeppoly_relu_kernel<<<grid, block, 0, stream>>>(
            (const f32x4*)x, (const f32x4*)lo, (const f32x4*)up,
            (f32x4*)x_out, (f32x4*)lo_out, (f32x4*)up_out, n4);
    }

    const int tail_start = n4 * 4;
    const int tail = n - tail_start;
    if (tail > 0) {
        deeppoly_relu_tail<<<(tail + 255) / 256, 256, 0, stream>>>(
            x, lo, up, x_out, lo_out, up_out, tail_start, n);
    }
}

// Round 4
// 71.032 us; speedup vs baseline: 1.1556x; 1.1556x over previous
//
#include <hip/hip_runtime.h>

// DeepPoly ReLU — HBM-bound streaming, 402.6 MB single-touch traffic.
// Round 4 experiment: split into two kernels to reduce concurrent stream
// count per phase. A: x_out=max(x,0) (1R+1W, copy-like). B: bounds (2R+2W).
// Block-contiguous unroll (each block streams a contiguous 32KB window per
// array) for DRAM page locality; nontemporal (streaming, no reuse).

#define U 8  // float4 per thread per tile

typedef float f32x4 __attribute__((ext_vector_type(4)));

__device__ __forceinline__ f32x4 nt_load(const f32x4* p) {
    return __builtin_nontemporal_load(p);
}
__device__ __forceinline__ void nt_store(f32x4* p, f32x4 v) {
    __builtin_nontemporal_store(v, p);
}

__device__ __forceinline__ void bounds_one(float lf, float uf,
                                           float& lo_o, float& up_o) {
    const bool neg = (uf <= 0.0f);          // fully inactive
    const bool pos = (lf >= 0.0f);          // fully active (after neg)
    const bool crossing = (!neg) && (!pos);
    const float denom = crossing ? (uf - lf) : 1.0f;  // >0 when crossing
    const float su = (uf / denom) * uf;     // slope*u, uniform (no divergence)
    lo_o = neg ? 0.0f : (pos ? uf : lf);
    up_o = neg ? 0.0f : (pos ? uf : su);
}

// ---- Kernel A: relu copy (2 streams) ----
__global__ void __launch_bounds__(256) relu_x_kernel(
    const f32x4* __restrict__ x, f32x4* __restrict__ x_out, int n4)
{
    const int tile = blockDim.x * U;             // 2048 float4 = 32 KiB
    const int ntiles = n4 / tile;
    for (int t = blockIdx.x; t < ntiles; t += gridDim.x) {
        const long long base = (long long)t * tile + threadIdx.x;
        f32x4 v[U];
        #pragma unroll
        for (int k = 0; k < U; ++k) v[k] = nt_load(&x[base + k * blockDim.x]);
        #pragma unroll
        for (int k = 0; k < U; ++k) {
            f32x4 r;
            r.x = fmaxf(v[k].x, 0.0f); r.y = fmaxf(v[k].y, 0.0f);
            r.z = fmaxf(v[k].z, 0.0f); r.w = fmaxf(v[k].w, 0.0f);
            nt_store(&x_out[base + k * blockDim.x], r);
        }
    }
    // leftover float4s
    const int rem = ntiles * tile;
    for (int i = rem + blockIdx.x * blockDim.x + threadIdx.x; i < n4;
         i += gridDim.x * blockDim.x) {
        f32x4 v = nt_load(&x[i]);
        f32x4 r;
        r.x = fmaxf(v.x, 0.0f); r.y = fmaxf(v.y, 0.0f);
        r.z = fmaxf(v.z, 0.0f); r.w = fmaxf(v.w, 0.0f);
        nt_store(&x_out[i], r);
    }
}

// ---- Kernel B: bounds (4 streams) ----
__global__ void __launch_bounds__(256) relu_bounds_kernel(
    const f32x4* __restrict__ lo, const f32x4* __restrict__ up,
    f32x4* __restrict__ lo_out, f32x4* __restrict__ up_out, int n4)
{
    const int tile = blockDim.x * U;
    const int ntiles = n4 / tile;
    for (int t = blockIdx.x; t < ntiles; t += gridDim.x) {
        const long long base = (long long)t * tile + threadIdx.x;
        f32x4 lv[U], uv[U];
        #pragma unroll
        for (int k = 0; k < U; ++k) {
            lv[k] = nt_load(&lo[base + k * blockDim.x]);
            uv[k] = nt_load(&up[base + k * blockDim.x]);
        }
        #pragma unroll
        for (int k = 0; k < U; ++k) {
            f32x4 lo_o, up_o;
            #pragma unroll
            for (int j = 0; j < 4; ++j) {
                float a, b;
                bounds_one(lv[k][j], uv[k][j], a, b);
                lo_o[j] = a; up_o[j] = b;
            }
            nt_store(&lo_out[base + k * blockDim.x], lo_o);
            nt_store(&up_out[base + k * blockDim.x], up_o);
        }
    }
    const int rem = ntiles * tile;
    for (int i = rem + blockIdx.x * blockDim.x + threadIdx.x; i < n4;
         i += gridDim.x * blockDim.x) {
        f32x4 lv = nt_load(&lo[i]);
        f32x4 uv = nt_load(&up[i]);
        f32x4 lo_o, up_o;
        #pragma unroll
        for (int j = 0; j < 4; ++j) {
            float a, b;
            bounds_one(lv[j], uv[j], a, b);
            lo_o[j] = a; up_o[j] = b;
        }
        nt_store(&lo_out[i], lo_o);
        nt_store(&up_out[i], up_o);
    }
}

// Scalar tail for N not divisible by 4 (not expected at N=16.7M).
__global__ void deeppoly_relu_tail(
    const float* __restrict__ x, const float* __restrict__ lo,
    const float* __restrict__ up, float* __restrict__ x_out,
    float* __restrict__ lo_out, float* __restrict__ up_out, int start, int n)
{
    int i = start + blockIdx.x * blockDim.x + threadIdx.x;
    if (i < n) {
        x_out[i] = fmaxf(x[i], 0.0f);
        float a, b;
        bounds_one(lo[i], up[i], a, b);
        lo_out[i] = a; up_out[i] = b;
    }
}

extern "C" void kernel_launch(void* const* d_in, const int* in_sizes, int n_in,
                              void* d_out, int out_size, void* d_ws, size_t ws_size,
                              hipStream_t stream) {
    const float* x  = (const float*)d_in[0];
    const float* lo = (const float*)d_in[1];
    const float* up = (const float*)d_in[2];
    float* out = (float*)d_out;

    const int n = in_sizes[0];
    float* x_out  = out;
    float* lo_out = out + (size_t)n;
    float* up_out = out + 2 * (size_t)n;

    const int n4 = n / 4;
    const int block = 256;
    const int tile = block * U;                  // 2048 float4
    const int ntiles = n4 / tile;                // 2048 at N=16.7M

    int gridA = ntiles > 0 ? (ntiles < 2048 ? ntiles : 2048) : 1;
    int gridB = ntiles > 0 ? (ntiles < 2048 ? ntiles : 2048) : 1;

    relu_x_kernel<<<gridA, block, 0, stream>>>(
        (const f32x4*)x, (f32x4*)x_out, n4);
    relu_bounds_kernel<<<gridB, block, 0, stream>>>(
        (const f32x4*)lo, (const f32x4*)up, (f32x4*)lo_out, (f32x4*)up_out, n4);

    const int tail_start = n4 * 4;
    const int tail = n - tail_start;
    if (tail > 0) {
        deeppoly_relu_tail<<<(tail + 255) / 256, 256, 0, stream>>>(
            x, lo, up, x_out, lo_out, up_out, tail_start, n);
    }
}